// Round 1
// baseline (499.648 us; speedup 1.0000x reference)
//
#include <hip/hip_runtime.h>

// RefWignerRotation: out[n, off + m*d + i, c] = sum_j D^l_n[i,j] * x[n, off + m*d + j, c]
// IRREPS: (l=0,mul=128) rows 0..127 | (l=1,64) rows 128..319 | (l=2,32) rows 320..479 | (l=3,16) rows 480..591
// DIM=592, C=16, N=8192. Memory-bound: 620 MB total traffic, roofline ~98us.
//
// v2 structure: async global_load_lds staging (linear) + LDS gather + linear stores.
//   - rows 0..127   : pure register copy (loads issued before staging burst)
//   - rows 128..591 : staged to LDS (1856 float4, 29.7 KB), gathered per output row
// D^l = A(alpha) * B(beta) * A(gamma); B entries are 7-term trig tables (CB below).

#define SAMPLE_F 9472      // 592*16 floats per sample
#define SAMPLE_F4 2368     // float4 per sample

// 83 D entries: l=1 -> t=0..8 (i*3+j), l=2 -> t=9..33 (9+i*5+j), l=3 -> t=34..82 (34+i*7+j)
// 7 coeffs each: (k0, cosb, sinb, cos2b, sin2b, cos3b, sin3b)
__device__ __constant__ float CB[83 * 7] = {
    // ---- l=1 (d=3) ----
    1,0,0,0,0,0,0,          // (0,0)
    0,0,0,0,0,0,0,          // (0,1)
    0,0,0,0,0,0,0,          // (0,2)
    0,0,0,0,0,0,0,          // (1,0)
    0,1,0,0,0,0,0,          // (1,1) cosb
    0,0,-1,0,0,0,0,         // (1,2) -sinb
    0,0,0,0,0,0,0,          // (2,0)
    0,0,1,0,0,0,0,          // (2,1) sinb
    0,1,0,0,0,0,0,          // (2,2) cosb
    // ---- l=2 (d=5) ----
    0,1,0,0,0,0,0,          // (0,0) cosb
    0,0,1,0,0,0,0,          // (0,1) sinb
    0,0,0,0,0,0,0,          // (0,2)
    0,0,0,0,0,0,0,          // (0,3)
    0,0,0,0,0,0,0,          // (0,4)
    0,0,-1,0,0,0,0,         // (1,0) -sinb
    0,1,0,0,0,0,0,          // (1,1) cosb
    0,0,0,0,0,0,0,          // (1,2)
    0,0,0,0,0,0,0,          // (1,3)
    0,0,0,0,0,0,0,          // (1,4)
    0,0,0,0,0,0,0,          // (2,0)
    0,0,0,0,0,0,0,          // (2,1)
    0.25f,0,0,0.75f,0,0,0,                         // (2,2)
    0,0,0,0,-0.8660254037844387f,0,0,              // (2,3)
    0.4330127018922193f,0,0,-0.4330127018922193f,0,0,0,  // (2,4)
    0,0,0,0,0,0,0,          // (3,0)
    0,0,0,0,0,0,0,          // (3,1)
    0,0,0,0,0.8660254037844387f,0,0,               // (3,2)
    0,0,0,1,0,0,0,                                 // (3,3) cos2b
    0,0,0,0,-0.5f,0,0,                             // (3,4)
    0,0,0,0,0,0,0,          // (4,0)
    0,0,0,0,0,0,0,          // (4,1)
    0.4330127018922193f,0,0,-0.4330127018922193f,0,0,0,  // (4,2)
    0,0,0,0,0.5f,0,0,                              // (4,3)
    0.75f,0,0,0.25f,0,0,0,                         // (4,4)
    // ---- l=3 (d=7) ----
    0.625f,0,0,0.375f,0,0,0,                       // (0,0)
    0,0,0,0,0.6123724356957945f,0,0,               // (0,1)
    0.4841229182759271f,0,0,-0.4841229182759271f,0,0,0,  // (0,2)
    0,0,0,0,0,0,0, 0,0,0,0,0,0,0, 0,0,0,0,0,0,0, 0,0,0,0,0,0,0, // (0,3..6)
    0,0,0,0,-0.6123724356957945f,0,0,              // (1,0)
    0,0,0,1,0,0,0,                                 // (1,1) cos2b
    0,0,0,0,0.7905694150420949f,0,0,               // (1,2)
    0,0,0,0,0,0,0, 0,0,0,0,0,0,0, 0,0,0,0,0,0,0, 0,0,0,0,0,0,0, // (1,3..6)
    0.4841229182759271f,0,0,-0.4841229182759271f,0,0,0,  // (2,0)
    0,0,0,0,-0.7905694150420949f,0,0,              // (2,1)
    0.375f,0,0,0.625f,0,0,0,                       // (2,2)
    0,0,0,0,0,0,0, 0,0,0,0,0,0,0, 0,0,0,0,0,0,0, 0,0,0,0,0,0,0, // (2,3..6)
    0,0,0,0,0,0,0, 0,0,0,0,0,0,0, 0,0,0,0,0,0,0,  // (3,0..2)
    0,0.375f,0,0,0,0.625f,0,                       // (3,3)
    0,0,-0.1530931089239487f,0,0,0,-0.7654655446197435f, // (3,4)
    0,0.4841229182759271f,0,0,0,-0.4841229182759271f,0,  // (3,5)
    0,0,-0.5929270612815711f,0,0,0,0.1976423537605237f,  // (3,6)
    0,0,0,0,0,0,0, 0,0,0,0,0,0,0, 0,0,0,0,0,0,0,  // (4,0..2)
    0,0,0.1530931089239487f,0,0,0,0.7654655446197435f,   // (4,3)
    0,0.0625f,0,0,0,0.9375f,0,                     // (4,4)
    0,0,0.1976423537605237f,0,0,0,-0.5929270612815711f,  // (4,5)
    0,0.2420614591379636f,0,0,0,-0.2420614591379636f,0,  // (4,6)
    0,0,0,0,0,0,0, 0,0,0,0,0,0,0, 0,0,0,0,0,0,0,  // (5,0..2)
    0,0.4841229182759271f,0,0,0,-0.4841229182759271f,0,  // (5,3)
    0,0,-0.1976423537605237f,0,0,0,0.5929270612815711f,  // (5,4)
    0,0.625f,0,0,0,0.375f,0,                       // (5,5)
    0,0,-0.7654655446197435f,0,0,0,-0.1530931089239487f, // (5,6)
    0,0,0,0,0,0,0, 0,0,0,0,0,0,0, 0,0,0,0,0,0,0,  // (6,0..2)
    0,0,0.5929270612815711f,0,0,0,-0.1976423537605237f,  // (6,3)
    0,0.2420614591379636f,0,0,0,-0.2420614591379636f,0,  // (6,4)
    0,0,0.7654655446197435f,0,0,0,0.1530931089239487f,   // (6,5)
    0,0.9375f,0,0,0,0.0625f,0,                     // (6,6)
};

__device__ __forceinline__ float4 f4_fma(float s, float4 x, float4 a) {
    a.x += s * x.x; a.y += s * x.y; a.z += s * x.z; a.w += s * x.w; return a;
}
__device__ __forceinline__ float4 f4_mul(float s, float4 x) {
    float4 r; r.x = s * x.x; r.y = s * x.y; r.z = s * x.z; r.w = s * x.w; return r;
}

#if defined(__has_builtin)
#if __has_builtin(__builtin_amdgcn_global_load_lds)
#define HAVE_GLOBAL_LOAD_LDS 1
#endif
#endif

#ifdef HAVE_GLOBAL_LOAD_LDS
// Async global->LDS, 16B per lane. LDS dest = wave-uniform base + lane*16 (linear);
// global src is per-lane. Counted by vmcnt; __syncthreads() drains it.
__device__ __forceinline__ void load_lds16(const float* g, float* l) {
    __builtin_amdgcn_global_load_lds(
        (const __attribute__((address_space(1))) void*)g,
        (__attribute__((address_space(3))) void*)l,
        16, 0, 0);
}
#endif

__global__ __launch_bounds__(256) void wigner_kernel(
    const float* __restrict__ x, const float* __restrict__ alpha,
    const float* __restrict__ beta, const float* __restrict__ gamma,
    float* __restrict__ out)
{
    __shared__ float4 sx4[1856];   // rows 128..591, linear: (row-128)*4 + c4
    __shared__ float sD[84];
    const int n = blockIdx.x;
    const int t = threadIdx.x;

    const float4* __restrict__ xs4 = (const float4*)(x + (size_t)n * SAMPLE_F);
    float4* __restrict__ os4 = (float4*)(out + (size_t)n * SAMPLE_F);

    // ---- l=0 copy loads FIRST (so their stores don't wait on staging vmcnt) ----
    const float4 c0 = xs4[t];
    const float4 c1 = xs4[t + 256];

    // ---- async stage rows 128..591 (1856 float4) linearly into LDS ----
    {
        const int w = t >> 6, lane = t & 63;
        const float* gst = x + (size_t)n * SAMPLE_F + 2048;  // row 128 starts at float 2048
        float* lb = (float*)sx4;
#ifdef HAVE_GLOBAL_LOAD_LDS
        #pragma unroll
        for (int k = 0; k < 7; ++k) {
            const int f4i = (w << 6) + (k << 8);             // wave-uniform chunk base
            load_lds16(gst + 4 * (f4i + lane), lb + 4 * f4i);
        }
        if (w == 0) load_lds16(gst + 4 * (1792 + lane), lb + 4 * 1792);
#else
        const float4* g4 = (const float4*)gst;
        #pragma unroll
        for (int k = 0; k < 7; ++k) {
            const int f4i = (w << 6) + (k << 8) + lane;
            sx4[f4i] = g4[f4i];
        }
        if (w == 0) sx4[1792 + lane] = g4[1792 + lane];
#endif
    }

    // ---- l=0 stores (rows 0..127), overlap with staging in flight ----
    os4[t] = c0;
    os4[t + 256] = c1;

    // ---------------- Phase 1: D entries -> LDS (threads 0..82) ----------------
    if (t < 83) {
        int l, i, j, base;
        if (t < 9)       { l = 1; base = 0;  int e = t;      i = e / 3; j = e - i * 3; }
        else if (t < 34) { l = 2; base = 9;  int e = t - 9;  i = e / 5; j = e - i * 5; }
        else             { l = 3; base = 34; int e = t - 34; i = e / 7; j = e - i * 7; }
        const int d = 2 * l + 1;

        const float a = alpha[n], b = beta[n], g = gamma[n];
        float cb1, sb1;
        __sincosf(b, &sb1, &cb1);
        const float cb2 = cb1 * cb1 - sb1 * sb1, sb2 = 2.f * sb1 * cb1;
        const float cb3 = cb2 * cb1 - sb2 * sb1, sb3 = sb2 * cb1 + cb2 * sb1;

        auto Bent = [&](int p, int q) -> float {
            const float* cc = &CB[(base + p * d + q) * 7];
            return cc[0] + cc[1] * cb1 + cc[2] * sb1 + cc[3] * cb2
                 + cc[4] * sb2 + cc[5] * cb3 + cc[6] * sb3;
        };

        const int ip = 2 * l - i, jp = 2 * l - j;
        float u, v;
        {
            const int mu = (i < l) ? (l - i) : (i - l);
            float sa, ca;
            __sincosf((float)mu * a, &sa, &ca);
            if (i < l)      { u = ca;  v = sa; }
            else if (i == l){ u = 1.f; v = 0.f; }
            else            { u = ca;  v = -sa; }
        }
        float p_, q_;
        {
            const int mu = (j < l) ? (l - j) : (j - l);
            float sg, cg;
            __sincosf((float)mu * g, &sg, &cg);
            if (j < l)      { p_ = cg;  q_ = -sg; }
            else if (j == l){ p_ = 1.f; q_ = 0.f; }
            else            { p_ = cg;  q_ = sg; }
        }
        const float Mij  = u * Bent(i, j)  + v * Bent(ip, j);
        const float Mijp = u * Bent(i, jp) + v * Bent(ip, jp);
        sD[t] = p_ * Mij + q_ * Mijp;
    }

    __syncthreads();   // drains vmcnt(0) (staging done) + lgkmcnt(0) (sD written)

    // ---------------- Phase 2: LDS gather, perfectly linear stores ----------------
    // Output chunk k covers o = 512 + 256k + t  (f4 index), r = o>>2 = 128 + 64k + rb.
    const int c4 = t & 3, rb = t >> 2;

    // k=0..2 : l=1 rows 128..319, e = r-128 = 64k+rb, m=e/3, i=e-3m
    #pragma unroll
    for (int k = 0; k < 3; ++k) {
        const int e = (k << 6) + rb;
        const int m = (int)((unsigned)e / 3u);
        const int i = e - 3 * m;
        const float4* xb = sx4 + m * 12 + c4;        // row-rel 3m
        const float* Dr = sD + i * 3;
        float4 y = f4_mul(Dr[0], xb[0]);
        y = f4_fma(Dr[1], xb[4], y);
        y = f4_fma(Dr[2], xb[8], y);
        os4[512 + (k << 8) + t] = y;
    }

    // k=3,4 : l=2 rows 320..447, e = r-320 = 64k+rb, m=e/5, i=e-5m
    #pragma unroll
    for (int k = 0; k < 2; ++k) {
        const int e = (k << 6) + rb;
        const int m = (int)((unsigned)e / 5u);
        const int i = e - 5 * m;
        const float4* xb = sx4 + (192 + m * 5) * 4 + c4;   // row-rel 192+5m
        const float* Dr = sD + 9 + i * 5;
        float4 y = f4_mul(Dr[0], xb[0]);
        #pragma unroll
        for (int j = 1; j < 5; ++j) y = f4_fma(Dr[j], xb[4 * j], y);
        os4[1280 + (k << 8) + t] = y;
    }

    // k=5 mixed: r = 448+rb; rb<32 -> l=2 (waves 0,1), rb>=32 -> l=3 (waves 2,3)
    {
        float4 y;
        if (rb < 32) {
            const int e = 128 + rb;
            const int m = (int)((unsigned)e / 5u);
            const int i = e - 5 * m;
            const float4* xb = sx4 + (192 + m * 5) * 4 + c4;
            const float* Dr = sD + 9 + i * 5;
            y = f4_mul(Dr[0], xb[0]);
            #pragma unroll
            for (int j = 1; j < 5; ++j) y = f4_fma(Dr[j], xb[4 * j], y);
        } else {
            const int e = rb - 32;                   // rows 480..511
            const int m = (int)((unsigned)e / 7u);
            const int i = e - 7 * m;
            const float4* xb = sx4 + (352 + m * 7) * 4 + c4;  // row-rel 352+7m
            const float* Dr = sD + 34 + i * 7;
            y = f4_mul(Dr[0], xb[0]);
            #pragma unroll
            for (int j = 1; j < 7; ++j) y = f4_fma(Dr[j], xb[4 * j], y);
        }
        os4[1792 + t] = y;
    }

    // k=6 : l=3 rows 512..575, e = 32+rb
    {
        const int e = 32 + rb;
        const int m = (int)((unsigned)e / 7u);
        const int i = e - 7 * m;
        const float4* xb = sx4 + (352 + m * 7) * 4 + c4;
        const float* Dr = sD + 34 + i * 7;
        float4 y = f4_mul(Dr[0], xb[0]);
        #pragma unroll
        for (int j = 1; j < 7; ++j) y = f4_fma(Dr[j], xb[4 * j], y);
        os4[2048 + t] = y;
    }

    // tail: t<64 (wave 0) -> rows 576..591, e = 96 + (t>>2)
    if (t < 64) {
        const int c4t = t & 3, rbt = t >> 2;
        const int e = 96 + rbt;
        const int m = (int)((unsigned)e / 7u);
        const int i = e - 7 * m;
        const float4* xb = sx4 + (352 + m * 7) * 4 + c4t;
        const float* Dr = sD + 34 + i * 7;
        float4 y = f4_mul(Dr[0], xb[0]);
        #pragma unroll
        for (int j = 1; j < 7; ++j) y = f4_fma(Dr[j], xb[4 * j], y);
        os4[2304 + t] = y;
    }
}

extern "C" void kernel_launch(void* const* d_in, const int* in_sizes, int n_in,
                              void* d_out, int out_size, void* d_ws, size_t ws_size,
                              hipStream_t stream) {
    const float* x     = (const float*)d_in[0];
    const float* alpha = (const float*)d_in[1];
    const float* beta  = (const float*)d_in[2];
    const float* gamma = (const float*)d_in[3];
    float* out = (float*)d_out;
    const int n = in_sizes[1];  // 8192 samples
    wigner_kernel<<<dim3(n), dim3(256), 0, stream>>>(x, alpha, beta, gamma, out);
}

// Round 2
// 498.925 us; speedup vs baseline: 1.0014x; 1.0014x over previous
//
#include <hip/hip_runtime.h>

// RefWignerRotation: out[n, off + m*d + i, c] = sum_j D^l_n[i,j] * x[n, off + m*d + j, c]
// IRREPS: (l=0,mul=128) rows 0..127 | (l=1,64) rows 128..319 | (l=2,32) rows 320..479 | (l=3,16) rows 480..591
// DIM=592, C=16, N=8192. Memory-bound: 620 MB total traffic, roofline ~98us.
//
// v3 structure:
//   - rows 0..127  (l=0): pure register copy (loads issued first)
//   - rows 128..319(l=1): pre-barrier, register-resident: direct loads + per-thread D1 + stores
//   - rows 320..591(l=2,3): async global_load_lds staging (17.4 KB, linear) + LDS gather,
//     perfectly linear stores. Only this part waits on the barrier.
// D^l = A(alpha) * B(beta) * A(gamma); B entries are 7-term trig tables (CB below).

#define SAMPLE_F 9472      // 592*16 floats per sample
#define SAMPLE_F4 2368     // float4 per sample

// Entries 9..82 used (l=2 -> 9+i*5+j, l=3 -> 34+i*7+j); l=1 (0..8) kept for layout but unused.
// 7 coeffs each: (k0, cosb, sinb, cos2b, sin2b, cos3b, sin3b)
__device__ __constant__ float CB[83 * 7] = {
    // ---- l=1 (d=3) ---- (unused by kernel, kept for index stability)
    1,0,0,0,0,0,0,
    0,0,0,0,0,0,0,
    0,0,0,0,0,0,0,
    0,0,0,0,0,0,0,
    0,1,0,0,0,0,0,
    0,0,-1,0,0,0,0,
    0,0,0,0,0,0,0,
    0,0,1,0,0,0,0,
    0,1,0,0,0,0,0,
    // ---- l=2 (d=5) ----
    0,1,0,0,0,0,0,          // (0,0) cosb
    0,0,1,0,0,0,0,          // (0,1) sinb
    0,0,0,0,0,0,0,          // (0,2)
    0,0,0,0,0,0,0,          // (0,3)
    0,0,0,0,0,0,0,          // (0,4)
    0,0,-1,0,0,0,0,         // (1,0) -sinb
    0,1,0,0,0,0,0,          // (1,1) cosb
    0,0,0,0,0,0,0,          // (1,2)
    0,0,0,0,0,0,0,          // (1,3)
    0,0,0,0,0,0,0,          // (1,4)
    0,0,0,0,0,0,0,          // (2,0)
    0,0,0,0,0,0,0,          // (2,1)
    0.25f,0,0,0.75f,0,0,0,                         // (2,2)
    0,0,0,0,-0.8660254037844387f,0,0,              // (2,3)
    0.4330127018922193f,0,0,-0.4330127018922193f,0,0,0,  // (2,4)
    0,0,0,0,0,0,0,          // (3,0)
    0,0,0,0,0,0,0,          // (3,1)
    0,0,0,0,0.8660254037844387f,0,0,               // (3,2)
    0,0,0,1,0,0,0,                                 // (3,3) cos2b
    0,0,0,0,-0.5f,0,0,                             // (3,4)
    0,0,0,0,0,0,0,          // (4,0)
    0,0,0,0,0,0,0,          // (4,1)
    0.4330127018922193f,0,0,-0.4330127018922193f,0,0,0,  // (4,2)
    0,0,0,0,0.5f,0,0,                              // (4,3)
    0.75f,0,0,0.25f,0,0,0,                         // (4,4)
    // ---- l=3 (d=7) ----
    0.625f,0,0,0.375f,0,0,0,                       // (0,0)
    0,0,0,0,0.6123724356957945f,0,0,               // (0,1)
    0.4841229182759271f,0,0,-0.4841229182759271f,0,0,0,  // (0,2)
    0,0,0,0,0,0,0, 0,0,0,0,0,0,0, 0,0,0,0,0,0,0, 0,0,0,0,0,0,0, // (0,3..6)
    0,0,0,0,-0.6123724356957945f,0,0,              // (1,0)
    0,0,0,1,0,0,0,                                 // (1,1) cos2b
    0,0,0,0,0.7905694150420949f,0,0,               // (1,2)
    0,0,0,0,0,0,0, 0,0,0,0,0,0,0, 0,0,0,0,0,0,0, 0,0,0,0,0,0,0, // (1,3..6)
    0.4841229182759271f,0,0,-0.4841229182759271f,0,0,0,  // (2,0)
    0,0,0,0,-0.7905694150420949f,0,0,              // (2,1)
    0.375f,0,0,0.625f,0,0,0,                       // (2,2)
    0,0,0,0,0,0,0, 0,0,0,0,0,0,0, 0,0,0,0,0,0,0, 0,0,0,0,0,0,0, // (2,3..6)
    0,0,0,0,0,0,0, 0,0,0,0,0,0,0, 0,0,0,0,0,0,0,  // (3,0..2)
    0,0.375f,0,0,0,0.625f,0,                       // (3,3)
    0,0,-0.1530931089239487f,0,0,0,-0.7654655446197435f, // (3,4)
    0,0.4841229182759271f,0,0,0,-0.4841229182759271f,0,  // (3,5)
    0,0,-0.5929270612815711f,0,0,0,0.1976423537605237f,  // (3,6)
    0,0,0,0,0,0,0, 0,0,0,0,0,0,0, 0,0,0,0,0,0,0,  // (4,0..2)
    0,0,0.1530931089239487f,0,0,0,0.7654655446197435f,   // (4,3)
    0,0.0625f,0,0,0,0.9375f,0,                     // (4,4)
    0,0,0.1976423537605237f,0,0,0,-0.5929270612815711f,  // (4,5)
    0,0.2420614591379636f,0,0,0,-0.2420614591379636f,0,  // (4,6)
    0,0,0,0,0,0,0, 0,0,0,0,0,0,0, 0,0,0,0,0,0,0,  // (5,0..2)
    0,0.4841229182759271f,0,0,0,-0.4841229182759271f,0,  // (5,3)
    0,0,-0.1976423537605237f,0,0,0,0.5929270612815711f,  // (5,4)
    0,0.625f,0,0,0,0.375f,0,                       // (5,5)
    0,0,-0.7654655446197435f,0,0,0,-0.1530931089239487f, // (5,6)
    0,0,0,0,0,0,0, 0,0,0,0,0,0,0, 0,0,0,0,0,0,0,  // (6,0..2)
    0,0,0.5929270612815711f,0,0,0,-0.1976423537605237f,  // (6,3)
    0,0.2420614591379636f,0,0,0,-0.2420614591379636f,0,  // (6,4)
    0,0,0.7654655446197435f,0,0,0,0.1530931089239487f,   // (6,5)
    0,0.9375f,0,0,0,0.0625f,0,                     // (6,6)
};

__device__ __forceinline__ float4 f4_fma(float s, float4 x, float4 a) {
    a.x += s * x.x; a.y += s * x.y; a.z += s * x.z; a.w += s * x.w; return a;
}
__device__ __forceinline__ float4 f4_mul(float s, float4 x) {
    float4 r; r.x = s * x.x; r.y = s * x.y; r.z = s * x.z; r.w = s * x.w; return r;
}

#if defined(__has_builtin)
#if __has_builtin(__builtin_amdgcn_global_load_lds)
#define HAVE_GLOBAL_LOAD_LDS 1
#endif
#endif

#ifdef HAVE_GLOBAL_LOAD_LDS
// Async global->LDS, 16B per lane. LDS dest = wave-uniform base + lane*16 (linear);
// global src is per-lane. Counted by vmcnt; __syncthreads() drains it.
__device__ __forceinline__ void load_lds16(const float* g, float* l) {
    __builtin_amdgcn_global_load_lds(
        (const __attribute__((address_space(1))) void*)g,
        (__attribute__((address_space(3))) void*)l,
        16, 0, 0);
}
#endif

__global__ __launch_bounds__(256) void wigner_kernel(
    const float* __restrict__ x, const float* __restrict__ alpha,
    const float* __restrict__ beta, const float* __restrict__ gamma,
    float* __restrict__ out)
{
    __shared__ float4 sx4[1088];   // rows 320..591, linear: (row-320)*4 + c4  (17408 B)
    __shared__ float sD[84];       // entries 9..82 (l=2, l=3)
    const int n = blockIdx.x;
    const int t = threadIdx.x;

    const float4* __restrict__ xs4 = (const float4*)(x + (size_t)n * SAMPLE_F);
    float4* __restrict__ os4 = (float4*)(out + (size_t)n * SAMPLE_F);

    // ---- l=0 copy loads FIRST ----
    const float4 c0 = xs4[t];
    const float4 c1 = xs4[t + 256];

    // ---- async stage rows 320..591 (1088 float4) linearly into LDS ----
    {
        const int w = t >> 6, lane = t & 63;
        const float* gst = x + (size_t)n * SAMPLE_F + 5120;  // row 320 = float 5120 = f4 1280
        float* lb = (float*)sx4;
#ifdef HAVE_GLOBAL_LOAD_LDS
        #pragma unroll
        for (int k = 0; k < 4; ++k) {
            const int f4i = (w << 6) + (k << 8);             // wave-uniform chunk base
            load_lds16(gst + 4 * (f4i + lane), lb + 4 * f4i);
        }
        if (w == 0) load_lds16(gst + 4 * (1024 + lane), lb + 4 * 1024);
#else
        const float4* g4 = (const float4*)gst;
        #pragma unroll
        for (int k = 0; k < 4; ++k) {
            const int f4i = (w << 6) + (k << 8) + lane;
            sx4[f4i] = g4[f4i];
        }
        if (w == 0) sx4[1024 + lane] = g4[1024 + lane];
#endif
    }

    // ---- l=1 direct loads (rows 128..319): thread t -> m=t>>2, c4=t&3 ----
    const int m1 = t >> 2, c41 = t & 3;
    const int r4g = (128 + 3 * m1) * 4 + c41;
    const float4 xv0 = xs4[r4g];
    const float4 xv1 = xs4[r4g + 4];
    const float4 xv2 = xs4[r4g + 8];

    // ---- l=0 stores (overlap with staging/l1 loads in flight) ----
    os4[t] = c0;
    os4[t + 256] = c1;

    // ---- per-thread D^1(alpha,beta,gamma): 3x3, fully in registers ----
    // A(a): [[ca,0,sa],[0,1,0],[-sa,0,ca]]; B(b): [[1,0,0],[0,cb,-sb],[0,sb,cb]]
    // M = A(a)*B; D = M * A(g)  (right-mult: D[:,0]=cg*M0-sg*M2, D[:,1]=M1, D[:,2]=sg*M0+cg*M2)
    const float a_ = alpha[n], b_ = beta[n], g_ = gamma[n];
    float sa, ca, sb, cb, sg, cg;
    __sincosf(a_, &sa, &ca);
    __sincosf(b_, &sb, &cb);
    __sincosf(g_, &sg, &cg);
    // M rows
    const float M00 = ca,      M01 = sa * sb, M02 = sa * cb;
    const float M10 = 0.f,     M11 = cb,      M12 = -sb;
    const float M20 = -sa,     M21 = ca * sb, M22 = ca * cb;
    // D entries
    const float D00 = cg * M00 - sg * M02, D01 = M01, D02 = sg * M00 + cg * M02;
    const float D10 = cg * M10 - sg * M12, D11 = M11, D12 = sg * M10 + cg * M12;
    const float D20 = cg * M20 - sg * M22, D21 = M21, D22 = sg * M20 + cg * M22;

    // ---------------- Phase 1: l=2/l=3 D entries -> LDS (threads 0..73) ----------------
    if (t < 74) {
        const int q = t + 9;          // entry index in CB table
        int l, i, j, base;
        if (q < 34) { l = 2; base = 9;  int e = q - 9;  i = e / 5; j = e - i * 5; }
        else        { l = 3; base = 34; int e = q - 34; i = e / 7; j = e - i * 7; }
        const int d = 2 * l + 1;

        const float cb2 = cb * cb - sb * sb, sb2 = 2.f * sb * cb;
        const float cb3 = cb2 * cb - sb2 * sb, sb3 = sb2 * cb + cb2 * sb;

        auto Bent = [&](int p, int qq) -> float {
            const float* cc = &CB[(base + p * d + qq) * 7];
            return cc[0] + cc[1] * cb + cc[2] * sb + cc[3] * cb2
                 + cc[4] * sb2 + cc[5] * cb3 + cc[6] * sb3;
        };

        const int ip = 2 * l - i, jp = 2 * l - j;
        float u, v;
        {
            const int mu = (i < l) ? (l - i) : (i - l);
            float sa2, ca2;
            __sincosf((float)mu * a_, &sa2, &ca2);
            if (i < l)      { u = ca2;  v = sa2; }
            else if (i == l){ u = 1.f;  v = 0.f; }
            else            { u = ca2;  v = -sa2; }
        }
        float p_, q_;
        {
            const int mu = (j < l) ? (l - j) : (j - l);
            float sg2, cg2;
            __sincosf((float)mu * g_, &sg2, &cg2);
            if (j < l)      { p_ = cg2;  q_ = -sg2; }
            else if (j == l){ p_ = 1.f;  q_ = 0.f; }
            else            { p_ = cg2;  q_ = sg2; }
        }
        const float Mij  = u * Bent(i, j)  + v * Bent(ip, j);
        const float Mijp = u * Bent(i, jp) + v * Bent(ip, jp);
        sD[q] = p_ * Mij + q_ * Mijp;
    }

    // ---- l=1 compute + stores (pre-barrier; overlaps staging latency) ----
    {
        float4 y;
        y = f4_mul(D00, xv0); y = f4_fma(D01, xv1, y); y = f4_fma(D02, xv2, y);
        os4[r4g] = y;
        y = f4_mul(D10, xv0); y = f4_fma(D11, xv1, y); y = f4_fma(D12, xv2, y);
        os4[r4g + 4] = y;
        y = f4_mul(D20, xv0); y = f4_fma(D21, xv1, y); y = f4_fma(D22, xv2, y);
        os4[r4g + 8] = y;
    }

    __syncthreads();   // drains vmcnt (staging done) + lgkmcnt (sD written)

    // ---------------- Phase 2: l=2/l=3 LDS gather, perfectly linear stores ----------------
    const int c4 = t & 3, rb = t >> 2;

    // chunks kk=0,1 : l=2 rows 320..447, e = 64*kk+rb, m=e/5, i=e-5m
    #pragma unroll
    for (int kk = 0; kk < 2; ++kk) {
        const int e = (kk << 6) + rb;
        const int m = (int)((unsigned)e / 5u);
        const int i = e - 5 * m;
        const float4* xb = sx4 + m * 20 + c4;        // row-rel 5m
        const float* Dr = sD + 9 + i * 5;
        float4 y = f4_mul(Dr[0], xb[0]);
        #pragma unroll
        for (int j = 1; j < 5; ++j) y = f4_fma(Dr[j], xb[4 * j], y);
        os4[1280 + (kk << 8) + t] = y;
    }

    // mixed chunk: outputs f4 1792+t, r = 448+rb; rb<32 -> l=2 (waves 0,1), rb>=32 -> l=3
    {
        float4 y;
        if (rb < 32) {
            const int e = 128 + rb;
            const int m = (int)((unsigned)e / 5u);
            const int i = e - 5 * m;
            const float4* xb = sx4 + m * 20 + c4;
            const float* Dr = sD + 9 + i * 5;
            y = f4_mul(Dr[0], xb[0]);
            #pragma unroll
            for (int j = 1; j < 5; ++j) y = f4_fma(Dr[j], xb[4 * j], y);
        } else {
            const int e = rb - 32;                   // rows 480..511
            const int m = (int)((unsigned)e / 7u);
            const int i = e - 7 * m;
            const float4* xb = sx4 + 640 + m * 28 + c4;  // row-rel 160+7m
            const float* Dr = sD + 34 + i * 7;
            y = f4_mul(Dr[0], xb[0]);
            #pragma unroll
            for (int j = 1; j < 7; ++j) y = f4_fma(Dr[j], xb[4 * j], y);
        }
        os4[1792 + t] = y;
    }

    // chunk: outputs f4 2048+t, l=3 rows 512..575, e = 32+rb
    {
        const int e = 32 + rb;
        const int m = (int)((unsigned)e / 7u);
        const int i = e - 7 * m;
        const float4* xb = sx4 + 640 + m * 28 + c4;
        const float* Dr = sD + 34 + i * 7;
        float4 y = f4_mul(Dr[0], xb[0]);
        #pragma unroll
        for (int j = 1; j < 7; ++j) y = f4_fma(Dr[j], xb[4 * j], y);
        os4[2048 + t] = y;
    }

    // tail: t<64 (wave 0) -> outputs f4 2304+t, rows 576..591, e = 96 + (t>>2)
    if (t < 64) {
        const int c4t = t & 3, rbt = t >> 2;
        const int e = 96 + rbt;
        const int m = (int)((unsigned)e / 7u);
        const int i = e - 7 * m;
        const float4* xb = sx4 + 640 + m * 28 + c4t;
        const float* Dr = sD + 34 + i * 7;
        float4 y = f4_mul(Dr[0], xb[0]);
        #pragma unroll
        for (int j = 1; j < 7; ++j) y = f4_fma(Dr[j], xb[4 * j], y);
        os4[2304 + t] = y;
    }
}

extern "C" void kernel_launch(void* const* d_in, const int* in_sizes, int n_in,
                              void* d_out, int out_size, void* d_ws, size_t ws_size,
                              hipStream_t stream) {
    const float* x     = (const float*)d_in[0];
    const float* alpha = (const float*)d_in[1];
    const float* beta  = (const float*)d_in[2];
    const float* gamma = (const float*)d_in[3];
    float* out = (float*)d_out;
    const int n = in_sizes[1];  // 8192 samples
    wigner_kernel<<<dim3(n), dim3(256), 0, stream>>>(x, alpha, beta, gamma, out);
}